// Round 8
// baseline (132.977 us; speedup 1.0000x reference)
//
#include <hip/hip_runtime.h>
#include <math.h>

typedef __attribute__((ext_vector_type(8))) _Float16 half8;
typedef __attribute__((ext_vector_type(4))) float f32x4;
typedef __attribute__((ext_vector_type(2))) float f32x2;

constexpr int B_   = 32768;
constexpr int NKPS = 14;
constexpr int DIM  = 42;
constexpr int H1_  = 1024;
constexpr int NDOF = 7;

__device__ __forceinline__ void gload_lds16(const _Float16* g, _Float16* l) {
    __builtin_amdgcn_global_load_lds(
        (const __attribute__((address_space(1))) void*)g,
        (__attribute__((address_space(3))) void*)l,
        16, 0, 0);
}

// ---------------------------------------------------------------------------
// K0: pack B = [W1_hi(42); W1_hi(42); W1_lo(42); b1_hi; b1_lo] (K=128 x N=1024
// f16) chunk-contiguous:
//   frag = (c*4+ks)*8 + w   (c = ntile>>3, w = ntile&7, ks = k/32)
//   B1f[(frag*64+lane)*8+j] = B[k=ks*32+(lane>>4)*8+j][n=(c*8+w)*16+(lane&15)]
// Chunks 0-3 = n[0,512) (128 KB), chunks 4-7 = n[512,1024).
// Also W2 [1024][7] -> W2p [1024][8] f32.
// ---------------------------------------------------------------------------
__global__ __launch_bounds__(256)
void prep_kernel(const float* __restrict__ W1, const float* __restrict__ b1,
                 const float* __restrict__ W2,
                 _Float16* __restrict__ B1f, float* __restrict__ W2p)
{
    const int T = blockIdx.x * 256 + threadIdx.x;
    if (T < 16384) {
        const int lane = T & 63;
        const int frag = T >> 6;          // 0..255
        const int w    = frag & 7;
        const int ks   = (frag >> 3) & 3;
        const int c    = frag >> 5;
        const int ntile = c * 8 + w;
        const int n     = ntile * 16 + (lane & 15);
        const int kbase = ks * 32 + ((lane >> 4) << 3);
        half8 s;
#pragma unroll
        for (int j = 0; j < 8; ++j) {
            const int k = kbase + j;
            _Float16 hv;
            if (k < 42) {
                hv = (_Float16)W1[k * H1_ + n];
            } else if (k < 84) {
                hv = (_Float16)W1[(k - 42) * H1_ + n];
            } else if (k < 126) {
                const float x = W1[(k - 84) * H1_ + n];
                const _Float16 hi = (_Float16)x;
                hv = (_Float16)(x - (float)hi);
            } else if (k == 126) {
                hv = (_Float16)b1[n];
            } else {
                const float x = b1[n];
                const _Float16 hi = (_Float16)x;
                hv = (_Float16)(x - (float)hi);
            }
            s[j] = hv;
        }
        *((half8*)(B1f + (long)T * 8)) = s;
    } else if (T < 16384 + 1024) {
        const int n = T - 16384;
#pragma unroll
        for (int d = 0; d < 7; ++d) W2p[n * 8 + d] = W2[n * 7 + d];
        W2p[n * 8 + 7] = 0.f;
    }
}

// ---------------------------------------------------------------------------
// K1: persistent MLP. 256 blocks (1/CU) x 512 thr. Block = (n-half bh,
// row-group bg of 256 rows). B-half (128 KB) staged into LDS ONCE via
// global_load_lds; then 4 row-tiles of 64, each barrier-free in the GEMM:
// per wave 4 ntiles x (ds_read frags + 16 MFMA + W2-global epilogue).
// Partial angles (per half) written to pang[bh][row][8].
// ---------------------------------------------------------------------------
__global__ __launch_bounds__(512, 2)
void mlp_kernel(const float* __restrict__ joints,
                const _Float16* __restrict__ B1f,
                const float* __restrict__ W2p,
                float* __restrict__ pang)
{
    __shared__ __align__(16) _Float16 Bl[65536];       // 128 KB: B half image
    __shared__ __align__(16) _Float16 Alds[64][136];   // 17 KB
    __shared__ __align__(16) float sbuf[64][8];        // 2 KB

    const int tid  = threadIdx.x;
    const int bh   = blockIdx.x & 1;        // n-half
    const int bg   = blockIdx.x >> 1;       // row-group 0..127
    const int lane = tid & 63;
    const int w    = tid >> 6;              // wave 0..7
    const int g    = lane >> 4;
    const int lm   = lane & 15;

    // ---- stage B half once: linear copy B1f[bh*65536 ..] -> Bl ----
    {
        const _Float16* bs = B1f + (long)bh * 65536 + tid * 8;
        _Float16* bd = Bl + w * 512;
#pragma unroll
        for (int i = 0; i < 16; ++i)
            gload_lds16(bs + i * 4096, bd + i * 4096);
    }

    for (int tile = 0; tile < 4; ++tile) {
        const long bm = (long)bg * 256 + tile * 64;

        ((float*)sbuf)[tid] = 0.f;

        // ---- stage A: x split [x_hi | x_lo | x_hi | 1 | 1] as f16 ----
        {
            const int r  = tid >> 3;      // 0..63
            const int c8 = tid & 7;
            const float* jr = joints + (bm + r) * DIM;
#pragma unroll
            for (int h2 = 0; h2 < 2; ++h2) {
                const int gi = c8 + h2 * 8;
                half8 s;
#pragma unroll
                for (int j = 0; j < 8; ++j) {
                    const int k = gi * 8 + j;
                    _Float16 hv;
                    if (k < 42) {
                        hv = (_Float16)(jr[k] - jr[k % 3]);
                    } else if (k < 84) {
                        const int km = k - 42;
                        const float x = jr[km] - jr[km % 3];
                        const _Float16 hi = (_Float16)x;
                        hv = (_Float16)(x - (float)hi);
                    } else if (k < 126) {
                        const int km = k - 84;
                        hv = (_Float16)(jr[km] - jr[km % 3]);
                    } else {
                        hv = (_Float16)1.0f;
                    }
                    s[j] = hv;
                }
                *((half8*)&Alds[r][gi * 8]) = s;
            }
        }
        __syncthreads();  // A visible; (tile 0: also drains B DMA via vmcnt(0))

        half8 a[4][4];
#pragma unroll
        for (int mt = 0; mt < 4; ++mt)
#pragma unroll
            for (int ks = 0; ks < 4; ++ks)
                a[mt][ks] = *((const half8*)&Alds[mt * 16 + lm][ks * 32 + g * 8]);

        f32x2 angp[4][4];
#pragma unroll
        for (int mt = 0; mt < 4; ++mt)
#pragma unroll
            for (int p = 0; p < 4; ++p) angp[mt][p] = (f32x2){0.f, 0.f};

        // ---- barrier-free GEMM over this wave's 4 local ntiles ----
#pragma unroll
        for (int t = 0; t < 4; ++t) {
            const int ntl = w * 4 + t;                    // 0..31
            const int fb  = (((ntl >> 3) * 32) + (ntl & 7)) * 512;
            half8 bfr[4];
#pragma unroll
            for (int ks = 0; ks < 4; ++ks)
                bfr[ks] = *((const half8*)&Bl[fb + ks * 4096 + lane * 8]);

            f32x4 acc[4];
#pragma unroll
            for (int mt = 0; mt < 4; ++mt) acc[mt] = (f32x4){0.f, 0.f, 0.f, 0.f};
#pragma unroll
            for (int ks = 0; ks < 4; ++ks)
#pragma unroll
                for (int mt = 0; mt < 4; ++mt)
                    acc[mt] = __builtin_amdgcn_mfma_f32_16x16x32_f16(bfr[ks], a[mt][ks], acc[mt], 0, 0, 0);

            // epilogue: lane holds h[n][m], n_g = bh*512 + ntl*16 + g*4 + r
#pragma unroll
            for (int r = 0; r < 4; ++r) {
                const long n_g = (long)bh * 512 + ntl * 16 + g * 4 + r;
                const f32x4 wa = *((const f32x4*)(W2p + n_g * 8));
                const f32x4 wb = *((const f32x4*)(W2p + n_g * 8 + 4));
                const f32x2 w01 = (f32x2){wa[0], wa[1]};
                const f32x2 w23 = (f32x2){wa[2], wa[3]};
                const f32x2 w45 = (f32x2){wb[0], wb[1]};
                const f32x2 w67 = (f32x2){wb[2], wb[3]};
#pragma unroll
                for (int mt = 0; mt < 4; ++mt) {
                    const float h = fmaxf(acc[mt][r], 0.f);
                    const f32x2 hv = (f32x2){h, h};
                    angp[mt][0] = __builtin_elementwise_fma(hv, w01, angp[mt][0]);
                    angp[mt][1] = __builtin_elementwise_fma(hv, w23, angp[mt][1]);
                    angp[mt][2] = __builtin_elementwise_fma(hv, w45, angp[mt][2]);
                    angp[mt][3] = __builtin_elementwise_fma(hv, w67, angp[mt][3]);
                }
            }
        }

        // ---- reduce across 4 lane-groups; accumulate per row in sbuf ----
        float red[4][8];
#pragma unroll
        for (int mt = 0; mt < 4; ++mt)
#pragma unroll
            for (int p = 0; p < 4; ++p) {
                red[mt][p * 2 + 0] = angp[mt][p][0];
                red[mt][p * 2 + 1] = angp[mt][p][1];
            }
#pragma unroll
        for (int mt = 0; mt < 4; ++mt)
#pragma unroll
            for (int i = 0; i < 8; ++i) {
                float v = red[mt][i];
                v += __shfl_xor(v, 16, 64);
                v += __shfl_xor(v, 32, 64);
                red[mt][i] = v;
            }
        if (lane < 16) {
#pragma unroll
            for (int mt = 0; mt < 4; ++mt)
#pragma unroll
                for (int i = 0; i < 8; ++i)
                    atomicAdd(&sbuf[mt * 16 + lane][i], red[mt][i]);
        }
        __syncthreads();

        // ---- write partial angles for this half ----
        {
            const int m = tid >> 3, d = tid & 7;
            pang[((long)bh * B_ + bm + m) * 8 + d] = sbuf[m][d];
        }
        __syncthreads();   // before next tile reuses Alds/sbuf
    }
}

// ---------------------------------------------------------------------------
// K2: per-row FK + Kabsch (f64 Jacobi). Sums the two angle halves + b2,
// writes angles and pose.
// ---------------------------------------------------------------------------
#define JROT(app, aqq, apq, arp, arq, v0p, v0q, v1p, v1q, v2p, v2q) do { \
    double _apq = (apq); \
    if (fabs(_apq) > 1e-300) { \
        double _tau = ((aqq) - (app)) / (2.0 * _apq); \
        double _t = ((_tau >= 0.0) ? 1.0 : -1.0) / (fabs(_tau) + sqrt(1.0 + _tau*_tau)); \
        double _c = 1.0 / sqrt(1.0 + _t*_t); \
        double _s = _t * _c; \
        (app) -= _t * _apq; \
        (aqq) += _t * _apq; \
        (apq) = 0.0; \
        { double _rp = (arp), _rq = (arq); \
          (arp) = _c*_rp - _s*_rq; (arq) = _s*_rp + _c*_rq; } \
        { double _v = (v0p); (v0p) = _c*_v - _s*(v0q); (v0q) = _s*_v + _c*(v0q); } \
        { double _v = (v1p); (v1p) = _c*_v - _s*(v1q); (v1q) = _s*_v + _c*(v1q); } \
        { double _v = (v2p); (v2p) = _c*_v - _s*(v2q); (v2q) = _s*_v + _c*(v2q); } \
    } \
} while (0)

#define SWAP_EIG(ea, eb, va0, vb0, va1, vb1, va2, vb2) do { \
    double _tm; \
    _tm = (ea); (ea) = (eb); (eb) = _tm; \
    _tm = (va0); (va0) = (vb0); (vb0) = _tm; \
    _tm = (va1); (va1) = (vb1); (vb1) = _tm; \
    _tm = (va2); (va2) = (vb2); (vb2) = _tm; \
} while (0)

__global__ __launch_bounds__(128)
void fk_kernel(const float* __restrict__ joints,
               const float* __restrict__ pang,
               const float* __restrict__ b2,
               float* __restrict__ out)
{
    const int b = blockIdx.x * 128 + threadIdx.x;
    if (b >= B_) return;

    const float* jr = joints + (long)b * DIM;
    const float j0x = jr[0], j0y = jr[1], j0z = jr[2];
    float q[DIM];
#pragma unroll
    for (int k = 0; k < NKPS; ++k) {
        q[3*k+0] = jr[3*k+0] - j0x;
        q[3*k+1] = jr[3*k+1] - j0y;
        q[3*k+2] = jr[3*k+2] - j0z;
    }

    float ang[NDOF];
#pragma unroll
    for (int d = 0; d < NDOF; ++d)
        ang[d] = pang[(long)b * 8 + d] + pang[((long)B_ + b) * 8 + d] + b2[d];

#pragma unroll
    for (int d = 0; d < NDOF; ++d) out[(long)b * NDOF + d] = ang[d];

    float R00=1.f,R01=0.f,R02=0.f, R10=0.f,R11=1.f,R12=0.f, R20=0.f,R21=0.f,R22=1.f;
    float px=0.f, py=0.f, pz=0.f;
    float Hr00=0.f,Hr01=0.f,Hr02=0.f,Hr10=0.f,Hr11=0.f,Hr12=0.f,Hr20=0.f,Hr21=0.f,Hr22=0.f;
    float sPx=0.f, sPy=0.f, sPz=0.f;
    const float LL[NDOF] = {0.333f,0.316f,0.384f,0.088f,0.107f,0.103f,0.1f};

#pragma unroll
    for (int j = 0; j < NDOF; ++j) {
        float s, c;
        sincosf(ang[j], &s, &c);
        if ((j & 1) == 0) {
            float a0=R00, a1=R01; R00 = c*a0 + s*a1; R01 = c*a1 - s*a0;
            float b0=R10, b1v=R11; R10 = c*b0 + s*b1v; R11 = c*b1v - s*b0;
            float c0=R20, c1=R21; R20 = c*c0 + s*c1; R21 = c*c1 - s*c0;
        } else {
            float a0=R00, a2=R02; R00 = c*a0 - s*a2; R02 = s*a0 + c*a2;
            float b0=R10, b2v=R12; R10 = c*b0 - s*b2v; R12 = s*b0 + c*b2v;
            float c0=R20, c2=R22; R20 = c*c0 - s*c2; R22 = s*c0 + c*c2;
        }
        px = fmaf(LL[j], R02, px);
        py = fmaf(LL[j], R12, py);
        pz = fmaf(LL[j], R22, pz);
        {
            const float qx = q[6*j+0], qy = q[6*j+1], qz = q[6*j+2];
            sPx += px; sPy += py; sPz += pz;
            Hr00 = fmaf(px, qx, Hr00); Hr01 = fmaf(px, qy, Hr01); Hr02 = fmaf(px, qz, Hr02);
            Hr10 = fmaf(py, qx, Hr10); Hr11 = fmaf(py, qy, Hr11); Hr12 = fmaf(py, qz, Hr12);
            Hr20 = fmaf(pz, qx, Hr20); Hr21 = fmaf(pz, qy, Hr21); Hr22 = fmaf(pz, qz, Hr22);
        }
        {
            const float ox = fmaf(0.05f, R00, px);
            const float oy = fmaf(0.05f, R10, py);
            const float oz = fmaf(0.05f, R20, pz);
            const float qx = q[6*j+3], qy = q[6*j+4], qz = q[6*j+5];
            sPx += ox; sPy += oy; sPz += oz;
            Hr00 = fmaf(ox, qx, Hr00); Hr01 = fmaf(ox, qy, Hr01); Hr02 = fmaf(ox, qz, Hr02);
            Hr10 = fmaf(oy, qx, Hr10); Hr11 = fmaf(oy, qy, Hr11); Hr12 = fmaf(oy, qz, Hr12);
            Hr20 = fmaf(oz, qx, Hr20); Hr21 = fmaf(oz, qy, Hr21); Hr22 = fmaf(oz, qz, Hr22);
        }
    }

    float sQx = 0.f, sQy = 0.f, sQz = 0.f;
#pragma unroll
    for (int n = 0; n < NKPS; ++n) { sQx += q[3*n+0]; sQy += q[3*n+1]; sQz += q[3*n+2]; }

    const double inv14 = 1.0 / 14.0;
    const double cpx = (double)sPx * inv14, cpy = (double)sPy * inv14, cpz = (double)sPz * inv14;
    const double cqx = (double)sQx * inv14, cqy = (double)sQy * inv14, cqz = (double)sQz * inv14;

    const double h00 = (double)Hr00 - 14.0*cpx*cqx, h01 = (double)Hr01 - 14.0*cpx*cqy, h02 = (double)Hr02 - 14.0*cpx*cqz;
    const double h10 = (double)Hr10 - 14.0*cpy*cqx, h11 = (double)Hr11 - 14.0*cpy*cqy, h12 = (double)Hr12 - 14.0*cpy*cqz;
    const double h20 = (double)Hr20 - 14.0*cpz*cqx, h21 = (double)Hr21 - 14.0*cpz*cqy, h22 = (double)Hr22 - 14.0*cpz*cqz;

    double m00 = h00*h00 + h10*h10 + h20*h20;
    double m01 = h00*h01 + h10*h11 + h20*h21;
    double m02 = h00*h02 + h10*h12 + h20*h22;
    double m11 = h01*h01 + h11*h11 + h21*h21;
    double m12 = h01*h02 + h11*h12 + h21*h22;
    double m22 = h02*h02 + h12*h12 + h22*h22;

    double v00=1.0, v01=0.0, v02=0.0;
    double v10=0.0, v11=1.0, v12=0.0;
    double v20=0.0, v21=0.0, v22=1.0;

#pragma unroll
    for (int sw = 0; sw < 5; ++sw) {
        JROT(m00, m11, m01, m02, m12, v00, v01, v10, v11, v20, v21);
        JROT(m00, m22, m02, m01, m12, v00, v02, v10, v12, v20, v22);
        JROT(m11, m22, m12, m01, m02, v01, v02, v11, v12, v21, v22);
    }

    double e0 = m00, e1 = m11, e2 = m22;
    if (e0 < e1) SWAP_EIG(e0, e1, v00, v01, v10, v11, v20, v21);
    if (e0 < e2) SWAP_EIG(e0, e2, v00, v02, v10, v12, v20, v22);
    if (e1 < e2) SWAP_EIG(e1, e2, v01, v02, v11, v12, v21, v22);

    const double s0 = sqrt(fmax(e0, 0.0));
    const double s1 = sqrt(fmax(e1, 0.0));
    const double s2 = sqrt(fmax(e2, 0.0));

    const double det = h00*(h11*h22 - h12*h21) - h01*(h10*h22 - h12*h20) + h02*(h10*h21 - h11*h20);
    const double dsg = (det >= 0.0) ? 1.0 : -1.0;

    const double tiny = 1e-30;
    const double g0 = 1.0 / fmax(s0, tiny);
    const double g1 = 1.0 / fmax(s1, tiny);
    const double g2 = dsg / fmax(s2, tiny);

    const double K00 = g0*v00*v00 + g1*v01*v01 + g2*v02*v02;
    const double K01 = g0*v00*v10 + g1*v01*v11 + g2*v02*v12;
    const double K02 = g0*v00*v20 + g1*v01*v21 + g2*v02*v22;
    const double K11 = g0*v10*v10 + g1*v11*v11 + g2*v12*v12;
    const double K12 = g0*v10*v20 + g1*v11*v21 + g2*v12*v22;
    const double K22 = g0*v20*v20 + g1*v21*v21 + g2*v22*v22;

    const double r00 = K00*h00 + K01*h01 + K02*h02;
    const double r01 = K00*h10 + K01*h11 + K02*h12;
    const double r02 = K00*h20 + K01*h21 + K02*h22;
    const double r10 = K01*h00 + K11*h01 + K12*h02;
    const double r11 = K01*h10 + K11*h11 + K12*h12;
    const double r12 = K01*h20 + K11*h21 + K12*h22;
    const double r20 = K02*h00 + K12*h01 + K22*h02;
    const double r21 = K02*h10 + K12*h11 + K22*h12;
    const double r22 = K02*h20 + K12*h21 + K22*h22;

    const double tx = cqx - (r00*cpx + r01*cpy + r02*cpz) + (double)j0x;
    const double ty = cqy - (r10*cpx + r11*cpy + r12*cpz) + (double)j0y;
    const double tz = cqz - (r20*cpx + r21*cpy + r22*cpz) + (double)j0z;

    float* po = out + (long)B_ * NDOF + (long)b * 16;
    po[0]  = (float)r00; po[1]  = (float)r01; po[2]  = (float)r02; po[3]  = (float)tx;
    po[4]  = (float)r10; po[5]  = (float)r11; po[6]  = (float)r12; po[7]  = (float)ty;
    po[8]  = (float)r20; po[9]  = (float)r21; po[10] = (float)r22; po[11] = (float)tz;
    po[12] = 0.f; po[13] = 0.f; po[14] = 0.f; po[15] = 1.f;
}

extern "C" void kernel_launch(void* const* d_in, const int* in_sizes, int n_in,
                              void* d_out, int out_size, void* d_ws, size_t ws_size,
                              hipStream_t stream) {
    const float* joints = (const float*)d_in[0];
    const float* W1     = (const float*)d_in[1];
    const float* b1     = (const float*)d_in[2];
    const float* W2     = (const float*)d_in[3];
    const float* b2     = (const float*)d_in[4];
    float* out = (float*)d_out;

    _Float16* B1f  = (_Float16*)d_ws;                         // 256 KB
    float*    W2p  = (float*)((char*)d_ws + 262144);          // 32 KB
    float*    pang = (float*)((char*)d_ws + 294912);          // 2 MB

    hipLaunchKernelGGL(prep_kernel, dim3(68), dim3(256), 0, stream,
                       W1, b1, W2, B1f, W2p);

    hipLaunchKernelGGL(mlp_kernel, dim3(256), dim3(512), 0, stream,
                       joints, B1f, W2p, pang);

    hipLaunchKernelGGL(fk_kernel, dim3(B_ / 128), dim3(128), 0, stream,
                       joints, pang, b2, out);
}

// Round 9
// 112.390 us; speedup vs baseline: 1.1832x; 1.1832x over previous
//
#include <hip/hip_runtime.h>
#include <math.h>

typedef __attribute__((ext_vector_type(8))) _Float16 half8;
typedef __attribute__((ext_vector_type(4))) float f32x4;
typedef __attribute__((ext_vector_type(2))) float f32x2;

constexpr int B_   = 32768;
constexpr int NKPS = 14;
constexpr int DIM  = 42;
constexpr int H1_  = 1024;
constexpr int NDOF = 7;

// ---------------------------------------------------------------------------
// K0: pack B = [W1_hi(42); W1_hi(42); W1_lo(42); b1_hi; b1_lo] (K=128 x N=1024
// f16) in per-lane fragment order, fragment index = ntile*4 + ks:
//   B1f[((ntile*4+ks)*64+lane)*8+j] = B[k=ks*32+(lane>>4)*8+j][n=ntile*16+(lane&15)]
// Also pads W2 [1024][7] -> W2p [1024][8] f32.
// ---------------------------------------------------------------------------
__global__ __launch_bounds__(256)
void prep_kernel(const float* __restrict__ W1, const float* __restrict__ b1,
                 const float* __restrict__ W2,
                 _Float16* __restrict__ B1f, float* __restrict__ W2p)
{
    const int T = blockIdx.x * 256 + threadIdx.x;
    if (T < 16384) {
        const int lane  = T & 63;
        const int frag  = T >> 6;          // 0..255
        const int ks    = frag & 3;
        const int ntile = frag >> 2;       // 0..63
        const int n     = ntile * 16 + (lane & 15);
        const int kbase = ks * 32 + ((lane >> 4) << 3);
        half8 s;
#pragma unroll
        for (int j = 0; j < 8; ++j) {
            const int k = kbase + j;
            _Float16 hv;
            if (k < 42) {
                hv = (_Float16)W1[k * H1_ + n];
            } else if (k < 84) {
                hv = (_Float16)W1[(k - 42) * H1_ + n];
            } else if (k < 126) {
                const float x = W1[(k - 84) * H1_ + n];
                const _Float16 hi = (_Float16)x;
                hv = (_Float16)(x - (float)hi);
            } else if (k == 126) {
                hv = (_Float16)b1[n];
            } else {
                const float x = b1[n];
                const _Float16 hi = (_Float16)x;
                hv = (_Float16)(x - (float)hi);
            }
            s[j] = hv;
        }
        *((half8*)(B1f + (long)T * 8)) = s;
    } else if (T < 16384 + 1024) {
        const int n = T - 16384;
#pragma unroll
        for (int d = 0; d < 7; ++d) W2p[n * 8 + d] = W2[n * 7 + d];
        W2p[n * 8 + 7] = 0.f;
    }
}

// ---- stage 64 rows of split-x into an Alds buffer ----
__device__ __forceinline__ void stage_A(const float* __restrict__ joints,
                                        long bm, int tid,
                                        _Float16 (*A)[136])
{
    const int r  = tid >> 3;      // 0..63
    const int c8 = tid & 7;
    const float* jr = joints + (bm + r) * DIM;
#pragma unroll
    for (int h2 = 0; h2 < 2; ++h2) {
        const int gi = c8 + h2 * 8;   // 0..15
        half8 s;
#pragma unroll
        for (int j = 0; j < 8; ++j) {
            const int k = gi * 8 + j;
            _Float16 hv;
            if (k < 42) {
                hv = (_Float16)(jr[k] - jr[k % 3]);
            } else if (k < 84) {
                const int km = k - 42;
                const float x = jr[km] - jr[km % 3];
                const _Float16 hi = (_Float16)x;
                hv = (_Float16)(x - (float)hi);
            } else if (k < 126) {
                const int km = k - 84;
                hv = (_Float16)(jr[km] - jr[km % 3]);
            } else {
                hv = (_Float16)1.0f;
            }
            s[j] = hv;
        }
        *((half8*)&A[r][gi * 8]) = s;
    }
}

// ---- one 64-row tile: MFMA GEMM1 + W2 epilogue + cross-group reduce ----
__device__ __forceinline__ void tile_compute(const _Float16 (*A)[136],
                                             const half8 (&bfr)[2][4],
                                             const float* __restrict__ W2p,
                                             int q, int w, int g, int lm, int lane,
                                             float (*sb)[8])
{
    f32x2 angp[4][4];
#pragma unroll
    for (int mt = 0; mt < 4; ++mt)
#pragma unroll
        for (int p = 0; p < 4; ++p) angp[mt][p] = (f32x2){0.f, 0.f};

    const int nb0 = (q * 16 + w * 2 + 0) * 16 + g * 4;
    const int nb1 = (q * 16 + w * 2 + 1) * 16 + g * 4;

#pragma unroll
    for (int mt = 0; mt < 4; ++mt) {
        half8 a[4];
#pragma unroll
        for (int ks = 0; ks < 4; ++ks)
            a[ks] = *((const half8*)&A[mt * 16 + lm][ks * 32 + g * 8]);

        f32x4 acc0 = (f32x4){0.f, 0.f, 0.f, 0.f};
        f32x4 acc1 = (f32x4){0.f, 0.f, 0.f, 0.f};
#pragma unroll
        for (int ks = 0; ks < 4; ++ks) {
            acc0 = __builtin_amdgcn_mfma_f32_16x16x32_f16(bfr[0][ks], a[ks], acc0, 0, 0, 0);
            acc1 = __builtin_amdgcn_mfma_f32_16x16x32_f16(bfr[1][ks], a[ks], acc1, 0, 0, 0);
        }

#pragma unroll
        for (int r = 0; r < 4; ++r) {
            {
                const long n = nb0 + r;
                const f32x4 wa = *((const f32x4*)(W2p + n * 8));
                const f32x4 wb = *((const f32x4*)(W2p + n * 8 + 4));
                const float h = fmaxf(acc0[r], 0.f);
                const f32x2 hv = (f32x2){h, h};
                angp[mt][0] = __builtin_elementwise_fma(hv, (f32x2){wa[0], wa[1]}, angp[mt][0]);
                angp[mt][1] = __builtin_elementwise_fma(hv, (f32x2){wa[2], wa[3]}, angp[mt][1]);
                angp[mt][2] = __builtin_elementwise_fma(hv, (f32x2){wb[0], wb[1]}, angp[mt][2]);
                angp[mt][3] = __builtin_elementwise_fma(hv, (f32x2){wb[2], wb[3]}, angp[mt][3]);
            }
            {
                const long n = nb1 + r;
                const f32x4 wa = *((const f32x4*)(W2p + n * 8));
                const f32x4 wb = *((const f32x4*)(W2p + n * 8 + 4));
                const float h = fmaxf(acc1[r], 0.f);
                const f32x2 hv = (f32x2){h, h};
                angp[mt][0] = __builtin_elementwise_fma(hv, (f32x2){wa[0], wa[1]}, angp[mt][0]);
                angp[mt][1] = __builtin_elementwise_fma(hv, (f32x2){wa[2], wa[3]}, angp[mt][1]);
                angp[mt][2] = __builtin_elementwise_fma(hv, (f32x2){wb[0], wb[1]}, angp[mt][2]);
                angp[mt][3] = __builtin_elementwise_fma(hv, (f32x2){wb[2], wb[3]}, angp[mt][3]);
            }
        }
    }

    // reduce over the 4 lane-groups (xor 16, 32), accumulate in LDS
    float red[4][8];
#pragma unroll
    for (int mt = 0; mt < 4; ++mt)
#pragma unroll
        for (int p = 0; p < 4; ++p) {
            red[mt][p * 2 + 0] = angp[mt][p][0];
            red[mt][p * 2 + 1] = angp[mt][p][1];
        }
#pragma unroll
    for (int mt = 0; mt < 4; ++mt)
#pragma unroll
        for (int i = 0; i < 8; ++i) {
            float v = red[mt][i];
            v += __shfl_xor(v, 16, 64);
            v += __shfl_xor(v, 32, 64);
            red[mt][i] = v;
        }
    if (lane < 16) {
#pragma unroll
        for (int mt = 0; mt < 4; ++mt)
#pragma unroll
            for (int i = 0; i < 8; ++i)
                atomicAdd(&sb[mt * 16 + lane][i], red[mt][i]);
    }
}

// ---------------------------------------------------------------------------
// K1: MLP, B-stationary. Grid 1024 = 4 hidden-quarters x 256 row-groups
// (XCD-swizzled so the 4 quarter-blocks of a row-group share an XCD L2).
// Wave w holds its 2 ntiles' B fragments in registers for the whole kernel;
// rows streamed as 2 x 64-row tiles with double-buffered Alds (3 barriers).
// Partial angles per quarter -> pang[q][row][8].
// ---------------------------------------------------------------------------
__global__ __launch_bounds__(512, 2)
void mlp_kernel(const float* __restrict__ joints,
                const _Float16* __restrict__ B1f,
                const float* __restrict__ W2p,
                float* __restrict__ pang)
{
    __shared__ __align__(16) _Float16 Alds[2][64][136];   // 34 KB
    __shared__ float sbuf[2][64][8];                      // 4 KB

    const int tid  = threadIdx.x;
    const int xcd  = blockIdx.x & 7;
    const int idx  = blockIdx.x >> 3;
    const int q    = idx >> 5;                 // hidden quarter 0..3
    const int rg   = xcd * 32 + (idx & 31);    // row-group 0..255
    const long bm0 = (long)rg * 128;

    const int lane = tid & 63;
    const int w    = tid >> 6;     // wave 0..7
    const int g    = lane >> 4;
    const int lm   = lane & 15;

    // ---- B fragments: once per block, wave-stationary (32 VGPRs) ----
    const half8* Bf = (const half8*)B1f;
    half8 bfr[2][4];
#pragma unroll
    for (int u = 0; u < 2; ++u)
#pragma unroll
        for (int ks = 0; ks < 4; ++ks)
            bfr[u][ks] = Bf[((q * 16 + w * 2 + u) * 4 + ks) * 64 + lane];

    ((float*)sbuf)[tid]       = 0.f;
    ((float*)sbuf)[512 + tid] = 0.f;

    stage_A(joints, bm0, tid, Alds[0]);
    __syncthreads();

    // tile 0 (stage tile 1 early so its latency hides under compute)
    stage_A(joints, bm0 + 64, tid, Alds[1]);
    tile_compute(Alds[0], bfr, W2p, q, w, g, lm, lane, sbuf[0]);
    __syncthreads();
    {
        const int m = tid >> 3, d = tid & 7;
        pang[((long)q * B_ + bm0 + m) * 8 + d] = sbuf[0][m][d];
    }

    // tile 1
    tile_compute(Alds[1], bfr, W2p, q, w, g, lm, lane, sbuf[1]);
    __syncthreads();
    {
        const int m = tid >> 3, d = tid & 7;
        pang[((long)q * B_ + bm0 + 64 + m) * 8 + d] = sbuf[1][m][d];
    }
}

// ---------------------------------------------------------------------------
// K2: per-row FK + Kabsch (f64 Jacobi). Sums the 4 quarter partials + b2.
// ---------------------------------------------------------------------------
#define JROT(app, aqq, apq, arp, arq, v0p, v0q, v1p, v1q, v2p, v2q) do { \
    double _apq = (apq); \
    if (fabs(_apq) > 1e-300) { \
        double _tau = ((aqq) - (app)) / (2.0 * _apq); \
        double _t = ((_tau >= 0.0) ? 1.0 : -1.0) / (fabs(_tau) + sqrt(1.0 + _tau*_tau)); \
        double _c = 1.0 / sqrt(1.0 + _t*_t); \
        double _s = _t * _c; \
        (app) -= _t * _apq; \
        (aqq) += _t * _apq; \
        (apq) = 0.0; \
        { double _rp = (arp), _rq = (arq); \
          (arp) = _c*_rp - _s*_rq; (arq) = _s*_rp + _c*_rq; } \
        { double _v = (v0p); (v0p) = _c*_v - _s*(v0q); (v0q) = _s*_v + _c*(v0q); } \
        { double _v = (v1p); (v1p) = _c*_v - _s*(v1q); (v1q) = _s*_v + _c*(v1q); } \
        { double _v = (v2p); (v2p) = _c*_v - _s*(v2q); (v2q) = _s*_v + _c*(v2q); } \
    } \
} while (0)

#define SWAP_EIG(ea, eb, va0, vb0, va1, vb1, va2, vb2) do { \
    double _tm; \
    _tm = (ea); (ea) = (eb); (eb) = _tm; \
    _tm = (va0); (va0) = (vb0); (vb0) = _tm; \
    _tm = (va1); (va1) = (vb1); (vb1) = _tm; \
    _tm = (va2); (va2) = (vb2); (vb2) = _tm; \
} while (0)

__global__ __launch_bounds__(256)
void fk_kernel(const float* __restrict__ joints,
               const float* __restrict__ pang,
               const float* __restrict__ b2,
               float* __restrict__ out)
{
    const int b = blockIdx.x * 256 + threadIdx.x;
    if (b >= B_) return;

    const float* jr = joints + (long)b * DIM;
    const float j0x = jr[0], j0y = jr[1], j0z = jr[2];
    float q[DIM];
#pragma unroll
    for (int k = 0; k < NKPS; ++k) {
        q[3*k+0] = jr[3*k+0] - j0x;
        q[3*k+1] = jr[3*k+1] - j0y;
        q[3*k+2] = jr[3*k+2] - j0z;
    }

    float ang[NDOF];
#pragma unroll
    for (int d = 0; d < NDOF; ++d)
        ang[d] = pang[((long)0 * B_ + b) * 8 + d]
               + pang[((long)1 * B_ + b) * 8 + d]
               + pang[((long)2 * B_ + b) * 8 + d]
               + pang[((long)3 * B_ + b) * 8 + d]
               + b2[d];

#pragma unroll
    for (int d = 0; d < NDOF; ++d) out[(long)b * NDOF + d] = ang[d];

    float R00=1.f,R01=0.f,R02=0.f, R10=0.f,R11=1.f,R12=0.f, R20=0.f,R21=0.f,R22=1.f;
    float px=0.f, py=0.f, pz=0.f;
    float Hr00=0.f,Hr01=0.f,Hr02=0.f,Hr10=0.f,Hr11=0.f,Hr12=0.f,Hr20=0.f,Hr21=0.f,Hr22=0.f;
    float sPx=0.f, sPy=0.f, sPz=0.f;
    const float LL[NDOF] = {0.333f,0.316f,0.384f,0.088f,0.107f,0.103f,0.1f};

#pragma unroll
    for (int j = 0; j < NDOF; ++j) {
        float s, c;
        sincosf(ang[j], &s, &c);
        if ((j & 1) == 0) {
            float a0=R00, a1=R01; R00 = c*a0 + s*a1; R01 = c*a1 - s*a0;
            float b0=R10, b1v=R11; R10 = c*b0 + s*b1v; R11 = c*b1v - s*b0;
            float c0=R20, c1=R21; R20 = c*c0 + s*c1; R21 = c*c1 - s*c0;
        } else {
            float a0=R00, a2=R02; R00 = c*a0 - s*a2; R02 = s*a0 + c*a2;
            float b0=R10, b2v=R12; R10 = c*b0 - s*b2v; R12 = s*b0 + c*b2v;
            float c0=R20, c2=R22; R20 = c*c0 - s*c2; R22 = s*c0 + c*c2;
        }
        px = fmaf(LL[j], R02, px);
        py = fmaf(LL[j], R12, py);
        pz = fmaf(LL[j], R22, pz);
        {
            const float qx = q[6*j+0], qy = q[6*j+1], qz = q[6*j+2];
            sPx += px; sPy += py; sPz += pz;
            Hr00 = fmaf(px, qx, Hr00); Hr01 = fmaf(px, qy, Hr01); Hr02 = fmaf(px, qz, Hr02);
            Hr10 = fmaf(py, qx, Hr10); Hr11 = fmaf(py, qy, Hr11); Hr12 = fmaf(py, qz, Hr12);
            Hr20 = fmaf(pz, qx, Hr20); Hr21 = fmaf(pz, qy, Hr21); Hr22 = fmaf(pz, qz, Hr22);
        }
        {
            const float ox = fmaf(0.05f, R00, px);
            const float oy = fmaf(0.05f, R10, py);
            const float oz = fmaf(0.05f, R20, pz);
            const float qx = q[6*j+3], qy = q[6*j+4], qz = q[6*j+5];
            sPx += ox; sPy += oy; sPz += oz;
            Hr00 = fmaf(ox, qx, Hr00); Hr01 = fmaf(ox, qy, Hr01); Hr02 = fmaf(ox, qz, Hr02);
            Hr10 = fmaf(oy, qx, Hr10); Hr11 = fmaf(oy, qy, Hr11); Hr12 = fmaf(oy, qz, Hr12);
            Hr20 = fmaf(oz, qx, Hr20); Hr21 = fmaf(oz, qy, Hr21); Hr22 = fmaf(oz, qz, Hr22);
        }
    }

    float sQx = 0.f, sQy = 0.f, sQz = 0.f;
#pragma unroll
    for (int n = 0; n < NKPS; ++n) { sQx += q[3*n+0]; sQy += q[3*n+1]; sQz += q[3*n+2]; }

    const double inv14 = 1.0 / 14.0;
    const double cpx = (double)sPx * inv14, cpy = (double)sPy * inv14, cpz = (double)sPz * inv14;
    const double cqx = (double)sQx * inv14, cqy = (double)sQy * inv14, cqz = (double)sQz * inv14;

    const double h00 = (double)Hr00 - 14.0*cpx*cqx, h01 = (double)Hr01 - 14.0*cpx*cqy, h02 = (double)Hr02 - 14.0*cpx*cqz;
    const double h10 = (double)Hr10 - 14.0*cpy*cqx, h11 = (double)Hr11 - 14.0*cpy*cqy, h12 = (double)Hr12 - 14.0*cpy*cqz;
    const double h20 = (double)Hr20 - 14.0*cpz*cqx, h21 = (double)Hr21 - 14.0*cpz*cqy, h22 = (double)Hr22 - 14.0*cpz*cqz;

    double m00 = h00*h00 + h10*h10 + h20*h20;
    double m01 = h00*h01 + h10*h11 + h20*h21;
    double m02 = h00*h02 + h10*h12 + h20*h22;
    double m11 = h01*h01 + h11*h11 + h21*h21;
    double m12 = h01*h02 + h11*h12 + h21*h22;
    double m22 = h02*h02 + h12*h12 + h22*h22;

    double v00=1.0, v01=0.0, v02=0.0;
    double v10=0.0, v11=1.0, v12=0.0;
    double v20=0.0, v21=0.0, v22=1.0;

#pragma unroll
    for (int sw = 0; sw < 5; ++sw) {
        JROT(m00, m11, m01, m02, m12, v00, v01, v10, v11, v20, v21);
        JROT(m00, m22, m02, m01, m12, v00, v02, v10, v12, v20, v22);
        JROT(m11, m22, m12, m01, m02, v01, v02, v11, v12, v21, v22);
    }

    double e0 = m00, e1 = m11, e2 = m22;
    if (e0 < e1) SWAP_EIG(e0, e1, v00, v01, v10, v11, v20, v21);
    if (e0 < e2) SWAP_EIG(e0, e2, v00, v02, v10, v12, v20, v22);
    if (e1 < e2) SWAP_EIG(e1, e2, v01, v02, v11, v12, v21, v22);

    const double s0 = sqrt(fmax(e0, 0.0));
    const double s1 = sqrt(fmax(e1, 0.0));
    const double s2 = sqrt(fmax(e2, 0.0));

    const double det = h00*(h11*h22 - h12*h21) - h01*(h10*h22 - h12*h20) + h02*(h10*h21 - h11*h20);
    const double dsg = (det >= 0.0) ? 1.0 : -1.0;

    const double tiny = 1e-30;
    const double g0 = 1.0 / fmax(s0, tiny);
    const double g1 = 1.0 / fmax(s1, tiny);
    const double g2 = dsg / fmax(s2, tiny);

    const double K00 = g0*v00*v00 + g1*v01*v01 + g2*v02*v02;
    const double K01 = g0*v00*v10 + g1*v01*v11 + g2*v02*v12;
    const double K02 = g0*v00*v20 + g1*v01*v21 + g2*v02*v22;
    const double K11 = g0*v10*v10 + g1*v11*v11 + g2*v12*v12;
    const double K12 = g0*v10*v20 + g1*v11*v21 + g2*v12*v22;
    const double K22 = g0*v20*v20 + g1*v21*v21 + g2*v22*v22;

    const double r00 = K00*h00 + K01*h01 + K02*h02;
    const double r01 = K00*h10 + K01*h11 + K02*h12;
    const double r02 = K00*h20 + K01*h21 + K02*h22;
    const double r10 = K01*h00 + K11*h01 + K12*h02;
    const double r11 = K01*h10 + K11*h11 + K12*h12;
    const double r12 = K01*h20 + K11*h21 + K12*h22;
    const double r20 = K02*h00 + K12*h01 + K22*h02;
    const double r21 = K02*h10 + K12*h11 + K22*h12;
    const double r22 = K02*h20 + K12*h21 + K22*h22;

    const double tx = cqx - (r00*cpx + r01*cpy + r02*cpz) + (double)j0x;
    const double ty = cqy - (r10*cpx + r11*cpy + r12*cpz) + (double)j0y;
    const double tz = cqz - (r20*cpx + r21*cpy + r22*cpz) + (double)j0z;

    float* po = out + (long)B_ * NDOF + (long)b * 16;
    po[0]  = (float)r00; po[1]  = (float)r01; po[2]  = (float)r02; po[3]  = (float)tx;
    po[4]  = (float)r10; po[5]  = (float)r11; po[6]  = (float)r12; po[7]  = (float)ty;
    po[8]  = (float)r20; po[9]  = (float)r21; po[10] = (float)r22; po[11] = (float)tz;
    po[12] = 0.f; po[13] = 0.f; po[14] = 0.f; po[15] = 1.f;
}

extern "C" void kernel_launch(void* const* d_in, const int* in_sizes, int n_in,
                              void* d_out, int out_size, void* d_ws, size_t ws_size,
                              hipStream_t stream) {
    const float* joints = (const float*)d_in[0];
    const float* W1     = (const float*)d_in[1];
    const float* b1     = (const float*)d_in[2];
    const float* W2     = (const float*)d_in[3];
    const float* b2     = (const float*)d_in[4];
    float* out = (float*)d_out;

    _Float16* B1f  = (_Float16*)d_ws;                         // 256 KB
    float*    W2p  = (float*)((char*)d_ws + 262144);          // 32 KB
    float*    pang = (float*)((char*)d_ws + 294912);          // 4 MB

    hipLaunchKernelGGL(prep_kernel, dim3(68), dim3(256), 0, stream,
                       W1, b1, W2, B1f, W2p);

    hipLaunchKernelGGL(mlp_kernel, dim3(1024), dim3(512), 0, stream,
                       joints, B1f, W2p, pang);

    hipLaunchKernelGGL(fk_kernel, dim3(B_ / 256), dim3(256), 0, stream,
                       joints, pang, b2, out);
}

// Round 12
// 43.243 us; speedup vs baseline: 3.0751x; 2.5990x over previous
//
#include <hip/hip_runtime.h>
#include <math.h>

typedef __attribute__((ext_vector_type(8))) _Float16 half8;
typedef __attribute__((ext_vector_type(4))) _Float16 half4;
typedef __attribute__((ext_vector_type(2))) __fp16   fp16x2;
typedef __attribute__((ext_vector_type(4))) float f32x4;

constexpr int B_   = 32768;
constexpr int NKPS = 14;
constexpr int DIM  = 42;
constexpr int H1_  = 1024;
constexpr int NDOF = 7;

__device__ __forceinline__ void gload_lds16(const _Float16* g, _Float16* l) {
    __builtin_amdgcn_global_load_lds(
        (const __attribute__((address_space(1))) void*)g,
        (__attribute__((address_space(3))) void*)l,
        16, 0, 0);
}

// ---------------------------------------------------------------------------
// K0: pack B = [W1_hi(42); W1_hi(42); W1_lo(42); b1_hi; b1_lo] (K=128 x N=1024
// f16) in per-lane fragment order, fragment index = ntile*4 + ks:
//   B1f[((ntile*4+ks)*64+lane)*8+j] = B[k=ks*32+(lane>>4)*8+j][n=ntile*16+(lane&15)]
// Also packs W2^T fragments (mfma_f32_16x16x16_f16 A-operand), SPLIT hi/lo:
//   W2Th/W2Tl[(ntile*64+lane)*4 + j] = hi/lo of W2[n=ntile*16+(lane>>4)*4+j][d=lane&15]
//   (d >= 7 -> 0)
// ---------------------------------------------------------------------------
__global__ __launch_bounds__(256)
void prep_kernel(const float* __restrict__ W1, const float* __restrict__ b1,
                 const float* __restrict__ W2,
                 _Float16* __restrict__ B1f,
                 _Float16* __restrict__ W2Th, _Float16* __restrict__ W2Tl)
{
    const int T = blockIdx.x * 256 + threadIdx.x;
    if (T < 16384) {
        const int lane  = T & 63;
        const int frag  = T >> 6;          // 0..255
        const int ks    = frag & 3;
        const int ntile = frag >> 2;       // 0..63
        const int n     = ntile * 16 + (lane & 15);
        const int kbase = ks * 32 + ((lane >> 4) << 3);
        half8 s;
#pragma unroll
        for (int j = 0; j < 8; ++j) {
            const int k = kbase + j;
            _Float16 hv;
            if (k < 42) {
                hv = (_Float16)W1[k * H1_ + n];
            } else if (k < 84) {
                hv = (_Float16)W1[(k - 42) * H1_ + n];
            } else if (k < 126) {
                const float x = W1[(k - 84) * H1_ + n];
                const _Float16 hi = (_Float16)x;
                hv = (_Float16)(x - (float)hi);
            } else if (k == 126) {
                hv = (_Float16)b1[n];
            } else {
                const float x = b1[n];
                const _Float16 hi = (_Float16)x;
                hv = (_Float16)(x - (float)hi);
            }
            s[j] = hv;
        }
        *((half8*)(B1f + (long)T * 8)) = s;
    } else if (T < 16384 + 4096) {
        const int idx   = T - 16384;       // ntile*64 + lane
        const int lane  = idx & 63;
        const int ntile = idx >> 6;
        const int d     = lane & 15;
        const int g     = lane >> 4;
        half4 sh, sl;
#pragma unroll
        for (int j = 0; j < 4; ++j) {
            const int n = ntile * 16 + g * 4 + j;
            float v = (d < 7) ? W2[n * 7 + d] : 0.0f;
            const _Float16 hi = (_Float16)v;
            sh[j] = hi;
            sl[j] = (_Float16)(v - (float)hi);
        }
        *((half4*)(W2Th + (long)idx * 4)) = sh;
        *((half4*)(W2Tl + (long)idx * 4)) = sl;
    }
}

// ---------------------------------------------------------------------------
// K1: MLP. Grid 256 (64 row-groups x 4 hidden-quarters) = 1 block/CU, one
// round. 512 thr / 8 waves; waves split M (64 rows each). B-quarter (64 KB)
// + W2T hi/lo quarters (16 KB) staged to LDS once via global_load_lds; A
// fragments built in registers (predicated 3-term f16 split). GEMM1: mfma
// 16x16x32 swapped -> C[n][m]. GEMM2: mfma 16x16x16, 3 terms
// (Wh*hh + Wh*hl + Wl*hh) -> full f32-accuracy. pang[nq][row][8].
// ---------------------------------------------------------------------------
__global__ __launch_bounds__(512, 2)
void mlp_kernel(const float* __restrict__ joints,
                const _Float16* __restrict__ B1f,
                const _Float16* __restrict__ W2Th,
                const _Float16* __restrict__ W2Tl,
                float* __restrict__ pang)
{
    __shared__ __align__(16) _Float16 Bq[32768];    // 64 KB: B-quarter image
    __shared__ __align__(16) _Float16 W2sh[4096];   // 8 KB
    __shared__ __align__(16) _Float16 W2sl[4096];   // 8 KB

    const int  tid  = threadIdx.x;
    const int  lane = tid & 63;
    const int  w    = tid >> 6;     // wave 0..7
    const int  g    = lane >> 4;    // 0..3
    const int  lm   = lane & 15;
    const int  nq   = blockIdx.x & 3;
    const int  rg   = blockIdx.x >> 2;
    const long bm   = (long)rg * 512;

    // ---- stage B-quarter: 8 x 1KB per wave, linear ----
    {
        const _Float16* gs = B1f + (long)nq * 32768 + w * 4096 + lane * 8;
        _Float16* ld = Bq + w * 4096;
#pragma unroll
        for (int i = 0; i < 8; ++i)
            gload_lds16(gs + i * 512, ld + i * 512);
    }
    // ---- stage W2T hi/lo quarters: 1 x 1KB per wave each ----
    gload_lds16(W2Th + (long)nq * 4096 + w * 512 + lane * 8, W2sh + w * 512);
    gload_lds16(W2Tl + (long)nq * 4096 + w * 512 + lane * 8, W2sl + w * 512);

    // ---- A fragments in registers (3-term split, predicated) ----
    // lane supplies B-operand elem x_split[k = ks*32 + g*8 + j] of row
    // bm + w*64 + mt*16 + lm.  Terms: k<42 hi | 42..83 lo | 84..125 hi | 1,1.
    half8 a[4][4];
#pragma unroll
    for (int mt = 0; mt < 4; ++mt) {
        const float* jr = joints + (bm + w * 64 + mt * 16 + lm) * DIM;
        const float q0 = jr[0], q1 = jr[1], q2 = jr[2];
#pragma unroll
        for (int ks = 0; ks < 4; ++ks) {
            half8 s;
#pragma unroll
            for (int j = 0; j < 8; ++j) {
                const int k  = ks * 32 + g * 8 + j;        // runtime (g)
                const int t1 = (k >= 42) ? 1 : 0;
                const int t2 = (k >= 84) ? 1 : 0;
                int ksrc = k - 42 * (t1 + t2);
                const int m3 = ksrc - 3 * ((ksrc * 21846) >> 16);  // ksrc % 3
                const float x0 = (m3 == 0) ? q0 : ((m3 == 1) ? q1 : q2);
                if (ksrc > 41) ksrc = 41;                  // OOB guard (bias lanes)
                const float xv = jr[ksrc] - x0;
                const _Float16 fh = (_Float16)xv;
                const _Float16 fl = (_Float16)(xv - (float)fh);
                _Float16 r = (t1 && !t2) ? fl : fh;
                if (k >= 126) r = (_Float16)1.0f;
                s[j] = r;
            }
            a[mt][ks] = s;
        }
    }
    __syncthreads();   // drains gload_lds (vmcnt 0) + barrier: LDS images ready

    // ---- main: 16 ntiles; GEMM1 mfma + GEMM2 mfma (3-term) ----
    f32x4 D2[4];
#pragma unroll
    for (int mt = 0; mt < 4; ++mt) D2[mt] = (f32x4){0.f, 0.f, 0.f, 0.f};

#pragma unroll
    for (int nt = 0; nt < 16; ++nt) {
        half8 bfr[4];
#pragma unroll
        for (int ks = 0; ks < 4; ++ks)
            bfr[ks] = *((const half8*)&Bq[((nt * 4 + ks) * 64 + lane) * 8]);
        const half4 wth = *((const half4*)&W2sh[(nt * 64 + lane) * 4]);
        const half4 wtl = *((const half4*)&W2sl[(nt * 64 + lane) * 4]);

#pragma unroll
        for (int mt = 0; mt < 4; ++mt) {
            f32x4 acc = (f32x4){0.f, 0.f, 0.f, 0.f};
#pragma unroll
            for (int ks = 0; ks < 4; ++ks)
                acc = __builtin_amdgcn_mfma_f32_16x16x32_f16(bfr[ks], a[mt][ks], acc, 0, 0, 0);

            // lane holds h[n = nt*16 + g*4 + r][m = lm] = acc[r]
            const float h0 = fmaxf(acc[0], 0.f);
            const float h1 = fmaxf(acc[1], 0.f);
            const float h2 = fmaxf(acc[2], 0.f);
            const float h3 = fmaxf(acc[3], 0.f);
            const fp16x2 p01 = __builtin_amdgcn_cvt_pkrtz(h0, h1);
            const fp16x2 p23 = __builtin_amdgcn_cvt_pkrtz(h2, h3);
            half4 bhi;
            bhi[0] = (_Float16)p01[0]; bhi[1] = (_Float16)p01[1];
            bhi[2] = (_Float16)p23[0]; bhi[3] = (_Float16)p23[1];
            const float l0 = h0 - (float)bhi[0];
            const float l1 = h1 - (float)bhi[1];
            const float l2 = h2 - (float)bhi[2];
            const float l3 = h3 - (float)bhi[3];
            const fp16x2 q01 = __builtin_amdgcn_cvt_pkrtz(l0, l1);
            const fp16x2 q23 = __builtin_amdgcn_cvt_pkrtz(l2, l3);
            half4 blo;
            blo[0] = (_Float16)q01[0]; blo[1] = (_Float16)q01[1];
            blo[2] = (_Float16)q23[0]; blo[3] = (_Float16)q23[1];

            D2[mt] = __builtin_amdgcn_mfma_f32_16x16x16f16(wth, bhi, D2[mt], 0, 0, 0);
            D2[mt] = __builtin_amdgcn_mfma_f32_16x16x16f16(wth, blo, D2[mt], 0, 0, 0);
            D2[mt] = __builtin_amdgcn_mfma_f32_16x16x16f16(wtl, bhi, D2[mt], 0, 0, 0);
        }
    }

    // ---- D2: lane holds ang_partial[d = g*4 + r][m = lm]; d<8 in g<2 ----
    if (g < 2) {
#pragma unroll
        for (int mt = 0; mt < 4; ++mt) {
            const long row = bm + w * 64 + mt * 16 + lm;
            *((f32x4*)(pang + ((long)nq * B_ + row) * 8 + g * 4)) = D2[mt];
        }
    }
}

// ---------------------------------------------------------------------------
// K2: per-row FK + Kabsch (f64 Jacobi). Sums the 4 quarter partials + b2.
// ---------------------------------------------------------------------------
#define JROT(app, aqq, apq, arp, arq, v0p, v0q, v1p, v1q, v2p, v2q) do { \
    double _apq = (apq); \
    if (fabs(_apq) > 1e-300) { \
        double _tau = ((aqq) - (app)) / (2.0 * _apq); \
        double _t = ((_tau >= 0.0) ? 1.0 : -1.0) / (fabs(_tau) + sqrt(1.0 + _tau*_tau)); \
        double _c = 1.0 / sqrt(1.0 + _t*_t); \
        double _s = _t * _c; \
        (app) -= _t * _apq; \
        (aqq) += _t * _apq; \
        (apq) = 0.0; \
        { double _rp = (arp), _rq = (arq); \
          (arp) = _c*_rp - _s*_rq; (arq) = _s*_rp + _c*_rq; } \
        { double _v = (v0p); (v0p) = _c*_v - _s*(v0q); (v0q) = _s*_v + _c*(v0q); } \
        { double _v = (v1p); (v1p) = _c*_v - _s*(v1q); (v1q) = _s*_v + _c*(v1q); } \
        { double _v = (v2p); (v2p) = _c*_v - _s*(v2q); (v2q) = _s*_v + _c*(v2q); } \
    } \
} while (0)

#define SWAP_EIG(ea, eb, va0, vb0, va1, vb1, va2, vb2) do { \
    double _tm; \
    _tm = (ea); (ea) = (eb); (eb) = _tm; \
    _tm = (va0); (va0) = (vb0); (vb0) = _tm; \
    _tm = (va1); (va1) = (vb1); (vb1) = _tm; \
    _tm = (va2); (va2) = (vb2); (vb2) = _tm; \
} while (0)

__global__ __launch_bounds__(128)
void fk_kernel(const float* __restrict__ joints,
               const float* __restrict__ pang,
               const float* __restrict__ b2,
               float* __restrict__ out)
{
    const int b = blockIdx.x * 128 + threadIdx.x;
    if (b >= B_) return;

    const float* jr = joints + (long)b * DIM;
    const float j0x = jr[0], j0y = jr[1], j0z = jr[2];
    float q[DIM];
#pragma unroll
    for (int k = 0; k < NKPS; ++k) {
        q[3*k+0] = jr[3*k+0] - j0x;
        q[3*k+1] = jr[3*k+1] - j0y;
        q[3*k+2] = jr[3*k+2] - j0z;
    }

    float ang[NDOF];
#pragma unroll
    for (int d = 0; d < NDOF; ++d)
        ang[d] = pang[((long)0 * B_ + b) * 8 + d]
               + pang[((long)1 * B_ + b) * 8 + d]
               + pang[((long)2 * B_ + b) * 8 + d]
               + pang[((long)3 * B_ + b) * 8 + d]
               + b2[d];

#pragma unroll
    for (int d = 0; d < NDOF; ++d) out[(long)b * NDOF + d] = ang[d];

    float R00=1.f,R01=0.f,R02=0.f, R10=0.f,R11=1.f,R12=0.f, R20=0.f,R21=0.f,R22=1.f;
    float px=0.f, py=0.f, pz=0.f;
    float Hr00=0.f,Hr01=0.f,Hr02=0.f,Hr10=0.f,Hr11=0.f,Hr12=0.f,Hr20=0.f,Hr21=0.f,Hr22=0.f;
    float sPx=0.f, sPy=0.f, sPz=0.f;
    const float LL[NDOF] = {0.333f,0.316f,0.384f,0.088f,0.107f,0.103f,0.1f};

#pragma unroll
    for (int j = 0; j < NDOF; ++j) {
        float s, c;
        sincosf(ang[j], &s, &c);
        if ((j & 1) == 0) {
            float a0=R00, a1=R01; R00 = c*a0 + s*a1; R01 = c*a1 - s*a0;
            float b0=R10, b1v=R11; R10 = c*b0 + s*b1v; R11 = c*b1v - s*b0;
            float c0=R20, c1=R21; R20 = c*c0 + s*c1; R21 = c*c1 - s*c0;
        } else {
            float a0=R00, a2=R02; R00 = c*a0 - s*a2; R02 = s*a0 + c*a2;
            float b0=R10, b2v=R12; R10 = c*b0 - s*b2v; R12 = s*b0 + c*b2v;
            float c0=R20, c2=R22; R20 = c*c0 - s*c2; R22 = s*c0 + c*c2;
        }
        px = fmaf(LL[j], R02, px);
        py = fmaf(LL[j], R12, py);
        pz = fmaf(LL[j], R22, pz);
        {
            const float qx = q[6*j+0], qy = q[6*j+1], qz = q[6*j+2];
            sPx += px; sPy += py; sPz += pz;
            Hr00 = fmaf(px, qx, Hr00); Hr01 = fmaf(px, qy, Hr01); Hr02 = fmaf(px, qz, Hr02);
            Hr10 = fmaf(py, qx, Hr10); Hr11 = fmaf(py, qy, Hr11); Hr12 = fmaf(py, qz, Hr12);
            Hr20 = fmaf(pz, qx, Hr20); Hr21 = fmaf(pz, qy, Hr21); Hr22 = fmaf(pz, qz, Hr22);
        }
        {
            const float ox = fmaf(0.05f, R00, px);
            const float oy = fmaf(0.05f, R10, py);
            const float oz = fmaf(0.05f, R20, pz);
            const float qx = q[6*j+3], qy = q[6*j+4], qz = q[6*j+5];
            sPx += ox; sPy += oy; sPz += oz;
            Hr00 = fmaf(ox, qx, Hr00); Hr01 = fmaf(ox, qy, Hr01); Hr02 = fmaf(ox, qz, Hr02);
            Hr10 = fmaf(oy, qx, Hr10); Hr11 = fmaf(oy, qy, Hr11); Hr12 = fmaf(oy, qz, Hr12);
            Hr20 = fmaf(oz, qx, Hr20); Hr21 = fmaf(oz, qy, Hr21); Hr22 = fmaf(oz, qz, Hr22);
        }
    }

    float sQx = 0.f, sQy = 0.f, sQz = 0.f;
#pragma unroll
    for (int n = 0; n < NKPS; ++n) { sQx += q[3*n+0]; sQy += q[3*n+1]; sQz += q[3*n+2]; }

    const double inv14 = 1.0 / 14.0;
    const double cpx = (double)sPx * inv14, cpy = (double)sPy * inv14, cpz = (double)sPz * inv14;
    const double cqx = (double)sQx * inv14, cqy = (double)sQy * inv14, cqz = (double)sQz * inv14;

    const double h00 = (double)Hr00 - 14.0*cpx*cqx, h01 = (double)Hr01 - 14.0*cpx*cqy, h02 = (double)Hr02 - 14.0*cpx*cqz;
    const double h10 = (double)Hr10 - 14.0*cpy*cqx, h11 = (double)Hr11 - 14.0*cpy*cqy, h12 = (double)Hr12 - 14.0*cpy*cqz;
    const double h20 = (double)Hr20 - 14.0*cpz*cqx, h21 = (double)Hr21 - 14.0*cpz*cqy, h22 = (double)Hr22 - 14.0*cpz*cqz;

    double m00 = h00*h00 + h10*h10 + h20*h20;
    double m01 = h00*h01 + h10*h11 + h20*h21;
    double m02 = h00*h02 + h10*h12 + h20*h22;
    double m11 = h01*h01 + h11*h11 + h21*h21;
    double m12 = h01*h02 + h11*h12 + h21*h22;
    double m22 = h02*h02 + h12*h12 + h22*h22;

    double v00=1.0, v01=0.0, v02=0.0;
    double v10=0.0, v11=1.0, v12=0.0;
    double v20=0.0, v21=0.0, v22=1.0;

#pragma unroll
    for (int sw = 0; sw < 5; ++sw) {
        JROT(m00, m11, m01, m02, m12, v00, v01, v10, v11, v20, v21);
        JROT(m00, m22, m02, m01, m12, v00, v02, v10, v12, v20, v22);
        JROT(m11, m22, m12, m01, m02, v01, v02, v11, v12, v21, v22);
    }

    double e0 = m00, e1 = m11, e2 = m22;
    if (e0 < e1) SWAP_EIG(e0, e1, v00, v01, v10, v11, v20, v21);
    if (e0 < e2) SWAP_EIG(e0, e2, v00, v02, v10, v12, v20, v22);
    if (e1 < e2) SWAP_EIG(e1, e2, v01, v02, v11, v12, v21, v22);

    const double s0 = sqrt(fmax(e0, 0.0));
    const double s1 = sqrt(fmax(e1, 0.0));
    const double s2 = sqrt(fmax(e2, 0.0));

    const double det = h00*(h11*h22 - h12*h21) - h01*(h10*h22 - h12*h20) + h02*(h10*h21 - h11*h20);
    const double dsg = (det >= 0.0) ? 1.0 : -1.0;

    const double tiny = 1e-30;
    const double g0 = 1.0 / fmax(s0, tiny);
    const double g1 = 1.0 / fmax(s1, tiny);
    const double g2 = dsg / fmax(s2, tiny);

    const double K00 = g0*v00*v00 + g1*v01*v01 + g2*v02*v02;
    const double K01 = g0*v00*v10 + g1*v01*v11 + g2*v02*v12;
    const double K02 = g0*v00*v20 + g1*v01*v21 + g2*v02*v22;
    const double K11 = g0*v10*v10 + g1*v11*v11 + g2*v12*v12;
    const double K12 = g0*v10*v20 + g1*v11*v21 + g2*v12*v22;
    const double K22 = g0*v20*v20 + g1*v21*v21 + g2*v22*v22;

    const double r00 = K00*h00 + K01*h01 + K02*h02;
    const double r01 = K00*h10 + K01*h11 + K02*h12;
    const double r02 = K00*h20 + K01*h21 + K02*h22;
    const double r10 = K01*h00 + K11*h01 + K12*h02;
    const double r11 = K01*h10 + K11*h11 + K12*h12;
    const double r12 = K01*h20 + K11*h21 + K12*h22;
    const double r20 = K02*h00 + K12*h01 + K22*h02;
    const double r21 = K02*h10 + K12*h11 + K22*h12;
    const double r22 = K02*h20 + K12*h21 + K22*h22;

    const double tx = cqx - (r00*cpx + r01*cpy + r02*cpz) + (double)j0x;
    const double ty = cqy - (r10*cpx + r11*cpy + r12*cpz) + (double)j0y;
    const double tz = cqz - (r20*cpx + r21*cpy + r22*cpz) + (double)j0z;

    float* po = out + (long)B_ * NDOF + (long)b * 16;
    po[0]  = (float)r00; po[1]  = (float)r01; po[2]  = (float)r02; po[3]  = (float)tx;
    po[4]  = (float)r10; po[5]  = (float)r11; po[6]  = (float)r12; po[7]  = (float)ty;
    po[8]  = (float)r20; po[9]  = (float)r21; po[10] = (float)r22; po[11] = (float)tz;
    po[12] = 0.f; po[13] = 0.f; po[14] = 0.f; po[15] = 1.f;
}

extern "C" void kernel_launch(void* const* d_in, const int* in_sizes, int n_in,
                              void* d_out, int out_size, void* d_ws, size_t ws_size,
                              hipStream_t stream) {
    const float* joints = (const float*)d_in[0];
    const float* W1     = (const float*)d_in[1];
    const float* b1     = (const float*)d_in[2];
    const float* W2     = (const float*)d_in[3];
    const float* b2     = (const float*)d_in[4];
    float* out = (float*)d_out;

    _Float16* B1f  = (_Float16*)d_ws;                         // 256 KB
    _Float16* W2Th = (_Float16*)((char*)d_ws + 262144);       // 32 KB
    _Float16* W2Tl = (_Float16*)((char*)d_ws + 294912);       // 32 KB
    float*    pang = (float*)((char*)d_ws + 327680);          // 4 MB

    hipLaunchKernelGGL(prep_kernel, dim3(80), dim3(256), 0, stream,
                       W1, b1, W2, B1f, W2Th, W2Tl);

    hipLaunchKernelGGL(mlp_kernel, dim3(256), dim3(512), 0, stream,
                       joints, B1f, W2Th, W2Tl, pang);

    hipLaunchKernelGGL(fk_kernel, dim3(B_ / 128), dim3(128), 0, stream,
                       joints, pang, b2, out);
}